// Round 6
// baseline (31.969 us; speedup 1.0000x reference)
//
#include <hip/hip_runtime.h>
#include <math.h>

#define NUM_HEADS 16
#define DIM_HID 64
#define NUM_GAUSS 251
#define W_SCA_COLS 320   // DIM_HID + 256
#define GP 20            // padded stride (floats): 80B, 16B-aligned, banks spread 8-way
#define RAD 0.16f        // window radius: dropped terms < exp(-8)*|w| ~ 2e-5 each
#define EPB 256          // edges per block (512 threads, 2 lanes/edge)

// ---------------------------------------------------------------------------
// Split-2 kernel: each edge handled by a LANE PAIR (lane h-half = (tid&1)*8).
// Rationale (r5 post-mortem): E=200K at 1 thr/edge = only 3 waves/SIMD ->
// latency-bound at 24us while all pipes idle. Split-2 doubles wave count and
// halves per-wave dependent work. Same 782-block grid (prologue count
// unchanged -- r4 lesson).
//
// Algebraic collapse (validated r2-r5, absmax 3.9e-3 vs 1.57e-2):
//   weff[h] = w_vec1[h,:] @ w_edge
//   vnorm block of out_sca = ||unit|| * A[o];  A = |weff| @ w_sca[:, :64]^T
//   out_vec[o,i] = B[o]*unit[i] -> output_vec = (sigmoid*B)^2 * ||unit||^2
// One-hot etype: tri_edge_feat is exact one_hot -> single table row.
// Gate: full acc[16] assembled across the lane pair via DPP quad_perm
// (VALU pipe, no LDS), weights via wave-uniform s_load.
// ---------------------------------------------------------------------------

__device__ __forceinline__ float dpp_swap1(float v) {
    int i = __float_as_int(v);
    i = __builtin_amdgcn_mov_dpp(i, 0xB1, 0xF, 0xF, true);  // quad_perm [1,0,3,2]
    return __int_as_float(i);
}

__global__ __launch_bounds__(512, 4) void edge_kernel(
    const int* __restrict__ idxA,     // [E]
    const int* __restrict__ idxB,     // [E]
    const float* __restrict__ feat,   // [E,5]
    const float* __restrict__ pos,    // [N,3]
    const float* __restrict__ w_edge, // [64]
    const float* __restrict__ w_vec1, // [64,64]
    const float* __restrict__ w_vec2, // [16,64]
    const float* __restrict__ w_sca,  // [16,320]
    const float* __restrict__ w_gate, // [16,16]
    const float* __restrict__ b_gate, // [16]
    float* __restrict__ out,
    int E)
{
    __shared__ __align__(16) float wg[NUM_GAUSS * GP]; // gauss slice: row g = 16 heads
    __shared__ __align__(16) float wt5[5 * 16];        // etype slice: [t][o]
    __shared__ __align__(16) float weff[64];
    __shared__ __align__(16) float As[16], Bs[16];

    const int tid = threadIdx.x;
    const int e  = blockIdx.x * EPB + (tid >> 1);
    const int h  = (tid & 1) * 8;            // this lane's head-half base
    const bool hi = (tid & 1);
    const bool active = (e < E);
    const int ec = active ? e : (E - 1);

    // --- early per-edge loads: hide latency under the prologue ---
    const int na = idxA[ec];
    const int nb = idxB[ec];
    const float f1 = feat[ec * 5 + 1];
    const float f2 = feat[ec * 5 + 2];
    const float f3 = feat[ec * 5 + 3];
    const float f4 = feat[ec * 5 + 4];

    // --- stage gauss slice: 4016 elems / 512 thr = 8 iters ---
    for (int j = tid; j < 16 * NUM_GAUSS; j += 512) {
        int o = j / NUM_GAUSS;          // magic-mul
        int g = j - o * NUM_GAUSS;
        wg[g * GP + o] = w_sca[o * W_SCA_COLS + DIM_HID + g];
    }
    // --- stage etype slice [t][o] ---
    if (tid < 80) {
        int t = tid >> 4, o = tid & 15;
        wt5[t * 16 + o] = w_sca[o * W_SCA_COLS + DIM_HID + NUM_GAUSS + t];
    }
    // --- fold: weff[h] = w_vec1[h,:] @ w_edge ---
    if (tid < 64) {
        const float4* wrow = (const float4*)(w_vec1 + tid * 64);
        float s = 0.f;
        #pragma unroll
        for (int c4 = 0; c4 < 16; ++c4) {
            float4 v = wrow[c4];
            s += v.x * w_edge[c4 * 4 + 0] + v.y * w_edge[c4 * 4 + 1]
               + v.z * w_edge[c4 * 4 + 2] + v.w * w_edge[c4 * 4 + 3];
        }
        weff[tid] = s;
    }
    __syncthreads();
    if (tid < 16) {
        const float4* srow = (const float4*)(w_sca + tid * W_SCA_COLS);
        const float4* vrow = (const float4*)(w_vec2 + tid * 64);
        float a2 = 0.f, b2 = 0.f;
        #pragma unroll
        for (int k4 = 0; k4 < 16; ++k4) {
            float4 sv = srow[k4];
            float4 vv = vrow[k4];
            float4 wv = *(const float4*)&weff[k4 * 4];
            a2 += fabsf(wv.x) * sv.x + fabsf(wv.y) * sv.y + fabsf(wv.z) * sv.z + fabsf(wv.w) * sv.w;
            b2 += wv.x * vv.x + wv.y * vv.y + wv.z * vv.z + wv.w * vv.w;
        }
        As[tid] = a2;
        Bs[tid] = b2;
    }
    __syncthreads();

    if (!active) return;

    // --- geometry ---
    const float ax = pos[na * 3 + 0], ay = pos[na * 3 + 1], az = pos[na * 3 + 2];
    const float bx = pos[nb * 3 + 0], by = pos[nb * 3 + 1], bz = pos[nb * 3 + 2];
    const float vx = ax - bx, vy = ay - by, vz = az - bz;
    const float d  = sqrtf(vx * vx + vy * vy + vz * vz);
    const float un = d / (d + 1e-7f);      // ||unit||
    const float u2 = un * un;

    // one-hot etype index (feat rows are exact one-hot)
    const int ti = (int)(f1 + 2.f * f2 + 3.f * f3 + 4.f * f4 + 0.5f);

    // --- acc[8] for own heads h..h+7 ---
    float acc[8];
    {
        const float4 a0 = *(const float4*)&As[h];
        const float4 a1 = *(const float4*)&As[h + 4];
        const float4 t0 = *(const float4*)&wt5[ti * 16 + h];
        const float4 t1 = *(const float4*)&wt5[ti * 16 + h + 4];
        acc[0] = fmaf(un, a0.x, t0.x); acc[1] = fmaf(un, a0.y, t0.y);
        acc[2] = fmaf(un, a0.z, t0.z); acc[3] = fmaf(un, a0.w, t0.w);
        acc[4] = fmaf(un, a1.x, t1.x); acc[5] = fmaf(un, a1.y, t1.y);
        acc[6] = fmaf(un, a1.z, t1.z); acc[7] = fmaf(un, a1.w, t1.w);
    }

    // --- gaussian window: exp(-312.5*(d-0.04g)^2) ---
    {
        const float C2 = -312.5f * 1.44269504088896340736f;  // coeff * log2(e)
        int glo = (int)ceilf((d - RAD) * 25.f);
        int ghi = (int)floorf((d + RAD) * 25.f);
        if (glo < 0) glo = 0;
        if (ghi > NUM_GAUSS - 1) ghi = NUM_GAUSS - 1;
        for (int g = glo; g <= ghi; ++g) {
            const float t = d - (float)g * 0.04f;
            const float w = exp2f(C2 * t * t);
            const float4* row = (const float4*)&wg[g * GP + h];
            const float4 w0 = row[0], w1 = row[1];
            acc[0] += w * w0.x; acc[1] += w * w0.y; acc[2] += w * w0.z; acc[3] += w * w0.w;
            acc[4] += w * w1.x; acc[5] += w * w1.y; acc[6] += w * w1.z; acc[7] += w * w1.w;
        }
    }

    // --- assemble full acc[16] across the lane pair (DPP swap + static merge) ---
    float full[16];
    #pragma unroll
    for (int i = 0; i < 8; ++i) {
        const float part = dpp_swap1(acc[i]);
        full[i]     = hi ? part   : acc[i];
        full[8 + i] = hi ? acc[i] : part;
    }

    // --- store out_sca early (own heads) ---
    float* o1 = out + (size_t)e * 16 + h;
    *(float4*)(o1 + 0) = make_float4(acc[0], acc[1], acc[2], acc[3]);
    *(float4*)(o1 + 4) = make_float4(acc[4], acc[5], acc[6], acc[7]);

    // --- Bs broadcast into regs ---
    const float4 bs0 = *(const float4*)&Bs[0];
    const float4 bs1 = *(const float4*)&Bs[4];
    const float4 bs2 = *(const float4*)&Bs[8];
    const float4 bs3 = *(const float4*)&Bs[12];
    const float bsr[16] = { bs0.x, bs0.y, bs0.z, bs0.w, bs1.x, bs1.y, bs1.z, bs1.w,
                            bs2.x, bs2.y, bs2.z, bs2.w, bs3.x, bs3.y, bs3.z, bs3.w };

    // --- gate (redundant all-16 per lane; weights wave-uniform s_load) ---
    const float NL2E = -1.44269504088896340736f;
    float ov[16];
    #pragma unroll
    for (int o = 0; o < 16; ++o) {
        float x = b_gate[o];
        #pragma unroll
        for (int p = 0; p < 16; ++p) x = fmaf(full[p], w_gate[o * 16 + p], x);
        const float gate = __builtin_amdgcn_rcpf(1.0f + exp2f(NL2E * x));
        const float gv = gate * bsr[o];
        ov[o] = gv * gv * u2;
    }

    // --- select own half (static-index cndmask), store output_vec ---
    float own[8];
    #pragma unroll
    for (int i = 0; i < 8; ++i) own[i] = hi ? ov[8 + i] : ov[i];
    float* o2 = out + (size_t)E * 16 + (size_t)e * 16 + h;
    *(float4*)(o2 + 0) = make_float4(own[0], own[1], own[2], own[3]);
    *(float4*)(o2 + 4) = make_float4(own[4], own[5], own[6], own[7]);
}

extern "C" void kernel_launch(void* const* d_in, const int* in_sizes, int n_in,
                              void* d_out, int out_size, void* d_ws, size_t ws_size,
                              hipStream_t stream) {
    const int*   idx    = (const int*)d_in[0];    // [2,E]
    const float* feat   = (const float*)d_in[1];  // [E,5]
    const float* pos    = (const float*)d_in[2];  // [N,3]
    const float* w_edge = (const float*)d_in[3];  // [64,1]
    const float* w_vec1 = (const float*)d_in[4];  // [64,64]
    const float* w_vec2 = (const float*)d_in[5];  // [16,64]
    const float* w_sca  = (const float*)d_in[6];  // [16,320]
    const float* w_gate = (const float*)d_in[7];  // [16,16]
    const float* b_gate = (const float*)d_in[8];  // [16]
    float* out = (float*)d_out;

    const int E = in_sizes[0] / 2;
    const int nblk = (E + EPB - 1) / EPB;
    edge_kernel<<<nblk, 512, 0, stream>>>(idx, idx + E, feat, pos,
                                          w_edge, w_vec1, w_vec2,
                                          w_sca, w_gate, b_gate, out, E);
}